// Round 3
// baseline (499.310 us; speedup 1.0000x reference)
//
#include <hip/hip_runtime.h>
#include <hip/hip_bf16.h>
#include <stdint.h>

#define NH 16
#define NE 64
#define BT 128

typedef __attribute__((ext_vector_type(8))) short short8;
typedef __attribute__((ext_vector_type(16))) float f32x16;
typedef __attribute__((ext_vector_type(4))) float float4v;

// LDS: KH [0,16K) KL [16K,32K) — K tile only (Q is lane-private, kept in regs)
// tile = 128 rows x 64 bf16 (128 B/row), XOR-swizzle byte ^= (row&7)<<4

__device__ __forceinline__ short8 lds_frag(const unsigned char* base, int row, int e0) {
    int off = row * 128 + e0 * 2;
    off ^= (row & 7) << 4;
    return *reinterpret_cast<const short8*>(base + off);
}

// split 8 fp32 (scaled) into bf16 hi/lo short8 fragments
__device__ __forceinline__ void split8(const float4v v0, const float4v v1, float sc,
                                       short8& hi, short8& lo) {
    float x[8];
    #pragma unroll
    for (int j = 0; j < 4; ++j) { x[j] = v0[j] * sc; x[4 + j] = v1[j] * sc; }
    #pragma unroll
    for (int j = 0; j < 8; ++j) {
        __hip_bfloat16 hh = __float2bfloat16(x[j]);
        unsigned short us;
        __builtin_memcpy(&us, &hh, 2);
        hi[j] = (short)us;
        float resid = x[j] - __bfloat162float(hh);
        __hip_bfloat16 ll = __float2bfloat16(resid);
        __builtin_memcpy(&us, &ll, 2);
        lo[j] = (short)us;
    }
}

__global__ __launch_bounds__(512, 8)
void bmm1_kernel(const float* __restrict__ Qg, const float* __restrict__ Kg,
                 float* __restrict__ out)
{
    __shared__ __align__(16) unsigned char lds[32768];

    // XCD-aware bijective remap: 16 tiles of one (b,h) panel land on one XCD.
    const int l  = blockIdx.x + 16 * blockIdx.y + 256 * blockIdx.z;  // 0..8191
    const int r8 = l & 7;
    const int g  = l >> 3;
    const int p  = r8 + 8 * (g >> 4);      // panel 0..511
    const int t  = g & 15;                 // tile 0..15
    const int b  = p >> 4, h = p & 15;
    const int tq = t >> 2, tk = t & 3;

    const int L = 256 + (b * 37) % 257;
    if (tq * BT >= L || tk * BT >= L) return;

    long long toff = 0, ooff = 0;
    for (int i = 0; i < b; ++i) {
        int Li = 256 + (i * 37) % 257;
        toff += Li;
        ooff += (long long)NH * Li * Li;
    }

    const int tid   = threadIdx.x;
    const int lane  = tid & 63;
    const int wave  = tid >> 6;          // 0..7
    const int wm    = wave >> 1;         // 0..3  row block of 32
    const int wn    = wave & 1;          // 0..1  col block of 64
    const int rlane = lane & 31;
    const int klane = lane >> 5;

    // ---- issue lane-private Q loads early (hidden under K staging) ----
    int rq = tq * BT + wm * 32 + rlane;
    if (rq >= L) rq = L - 1;
    const float* qrow = Qg + (size_t)(toff + rq) * (NH * NE) + h * NE + klane * 8;
    float4v qv[4][2];
    #pragma unroll
    for (int ec = 0; ec < 4; ++ec) {
        qv[ec][0] = *reinterpret_cast<const float4v*>(qrow + ec * 16);
        qv[ec][1] = *reinterpret_cast<const float4v*>(qrow + ec * 16 + 4);
    }

    // ---- stage K tile into LDS as bf16 hi/lo ----
    {
        unsigned char* hibase = lds;
        unsigned char* lobase = lds + 16384;
        const int t0 = tk * BT;
        #pragma unroll
        for (int it = 0; it < 4; ++it) {
            int r  = (tid >> 4) + it * 32;       // row within tile, 0..127
            int rr = t0 + r;
            if (rr >= L) rr = L - 1;
            const float4v v = *reinterpret_cast<const float4v*>(
                Kg + (size_t)(toff + rr) * (NH * NE) + h * NE + (tid & 15) * 4);
            unsigned int hp[2], lp[2];
            #pragma unroll
            for (int j = 0; j < 2; ++j) {
                unsigned short hb[2], lb[2];
                #pragma unroll
                for (int jj = 0; jj < 2; ++jj) {
                    float x = v[j * 2 + jj];
                    __hip_bfloat16 hh = __float2bfloat16(x);
                    unsigned short us;
                    __builtin_memcpy(&us, &hh, 2);
                    hb[jj] = us;
                    float resid = x - __bfloat162float(hh);
                    __hip_bfloat16 ll = __float2bfloat16(resid);
                    __builtin_memcpy(&us, &ll, 2);
                    lb[jj] = us;
                }
                hp[j] = (unsigned int)hb[0] | ((unsigned int)hb[1] << 16);
                lp[j] = (unsigned int)lb[0] | ((unsigned int)lb[1] << 16);
            }
            int boff = r * 128 + (tid & 15) * 8;
            boff ^= (r & 7) << 4;
            *reinterpret_cast<uint2*>(hibase + boff) = make_uint2(hp[0], hp[1]);
            *reinterpret_cast<uint2*>(lobase + boff) = make_uint2(lp[0], lp[1]);
        }
    }
    __syncthreads();

    const unsigned char* KH = lds;
    const unsigned char* KL = lds + 16384;

    f32x16 acc[2];
    acc[0] = (f32x16)0.0f;
    acc[1] = (f32x16)0.0f;

    #pragma unroll
    for (int ec = 0; ec < 4; ++ec) {
        const int e0 = ec * 16 + klane * 8;
        short8 ah, al;
        split8(qv[ec][0], qv[ec][1], 0.125f, ah, al);   // SCALE folded into Q (exact pow2)
        #pragma unroll
        for (int nb = 0; nb < 2; ++nb) {
            const int brow = wn * 64 + nb * 32 + rlane;
            short8 bh = lds_frag(KH, brow, e0);
            short8 bl = lds_frag(KL, brow, e0);
            acc[nb] = __builtin_amdgcn_mfma_f32_32x32x16_bf16(ah, bh, acc[nb], 0, 0, 0);
            acc[nb] = __builtin_amdgcn_mfma_f32_32x32x16_bf16(ah, bl, acc[nb], 0, 0, 0);
            acc[nb] = __builtin_amdgcn_mfma_f32_32x32x16_bf16(al, bh, acc[nb], 0, 0, 0);
        }
    }

    // ---- store: C layout col=lane&31, row=(r&3)+8*(r>>2)+4*(lane>>5) ----
    const long long LL = L;
    float* obase = out + ooff + (long long)h * L * L;
    const int row0 = tq * BT + wm * 32 + 4 * klane;
    const bool interior = (tq * BT + BT <= L) && (tk * BT + BT <= L);

    if (interior) {
        #pragma unroll
        for (int nb = 0; nb < 2; ++nb) {
            const int colg = tk * BT + wn * 64 + nb * 32 + rlane;
            float* rp = obase + (long long)row0 * LL + colg;
            #pragma unroll
            for (int rr = 0; rr < 16; ++rr) {
                const int c = (rr & 3) + 8 * (rr >> 2);   // uniform row offset
                rp[(long long)c * LL] = acc[nb][rr];
            }
        }
    } else {
        #pragma unroll
        for (int nb = 0; nb < 2; ++nb) {
            const int colg = tk * BT + wn * 64 + nb * 32 + rlane;
            if (colg >= L) continue;
            #pragma unroll
            for (int rr = 0; rr < 16; ++rr) {
                const int rowg = row0 + (rr & 3) + 8 * (rr >> 2);
                if (rowg < L)
                    obase[(long long)rowg * LL + colg] = acc[nb][rr];
            }
        }
    }
}

extern "C" void kernel_launch(void* const* d_in, const int* in_sizes, int n_in,
                              void* d_out, int out_size, void* d_ws, size_t ws_size,
                              hipStream_t stream) {
    const float* Qg = (const float*)d_in[0];   // batch1 [NTOKENS, H*E] fp32
    const float* Kg = (const float*)d_in[1];   // batch2 [NTOKENS, H*E] fp32
    float* out = (float*)d_out;                // ragged fp32, sum_b H*L_b^2
    dim3 grid(16, NH, 32);                     // remapped in-kernel (bijective)
    bmm1_kernel<<<grid, 512, 0, stream>>>(Qg, Kg, out);
}